// Round 6
// baseline (69.799 us; speedup 1.0000x reference)
//
#include <hip/hip_runtime.h>

#define BB 1024
#define DD 512
#define BT 64     // batch rows per block
#define JT 128    // j columns per block
#define KT 32     // i depth per block
#define NIC (DD / KT)               // 16 i-chunks
#define NTP ((DD / JT) * NIC)       // 64 t-partials per b
#define NNP (NIC * 4)               // 64 norm-partials per b (ic x wave)
// ws rows: [0,64) t partials, [64,128) norm partials; layout [row][b].

// out[b] = ||x_dot[b]||^2 + t[b]^2,  t[b] = sum_{i,j} x_dot[b,i] W[i,j] x[b,j]
// k1: block (rg,jc,ic) computes the t-partial over its (i,j) rectangle.
// 8x4 per-thread register tile: 3 ds_read_b128 per 32 FMA (1.5 LDS-B/FMA,
// vs 2.0 in the 4x4 version) — k1 is LDS-pipe-bound, so bytes/FMA is the knob.
// acc = 32 VGPRs (the 64-float acc of R3 spilled; stay at 32).
__global__ __launch_bounds__(256, 4) void stm_main_kernel(
    const float* __restrict__ x, const float* __restrict__ xdot,
    const float* __restrict__ W, float* __restrict__ ws_t) {
  __shared__ float xd_t[KT][BT];   // 8 KB, transposed x_dot chunk [i][b]
  __shared__ float w_s[KT][JT];    // 16 KB W tile

  const int tid = threadIdx.x;
  const int b0 = blockIdx.x * BT;
  const int j0 = blockIdx.y * JT;
  const int i0 = blockIdx.z * KT;
  const int tb = tid >> 5;   // 0..7  -> rows b0 + 8*tb .. +7
  const int tj = tid & 31;   // 0..31 -> cols j0 + 4*tj .. +3
  const int wv = tid >> 6, lane = tid & 63;

  // Stage x_dot chunk transposed: rows b0..b0+63 (row = lane -> transpose
  // writes hit bank = lane%32, conflict-free), cols i0..i0+31.
  // Accumulate this thread's 8 squared elements: they all belong to row
  // `lane`, so the per-(ic,wave) norm partial is a single per-lane store.
  float nrm = 0.f;
  {
    const float* src = xdot + (size_t)(b0 + lane) * DD + i0;
#pragma unroll
    for (int p = 0; p < 2; ++p) {
      const int c4 = wv + p * 4;        // 0..7
      const float4 v = *(const float4*)(src + c4 * 4);
      nrm += v.x * v.x + v.y * v.y + v.z * v.z + v.w * v.w;
      const int c = c4 * 4;
      xd_t[c + 0][lane] = v.x; xd_t[c + 1][lane] = v.y;
      xd_t[c + 2][lane] = v.z; xd_t[c + 3][lane] = v.w;
    }
  }
  // Stage W tile: 32 x 128 = 1024 float4, 4 per thread (coalesced).
#pragma unroll
  for (int v = 0; v < 4; ++v) {
    const int f4 = tid + v * 256;
    const int ii = f4 >> 5, jj4 = f4 & 31;
    *(float4*)&w_s[ii][jj4 * 4] =
        *(const float4*)(W + (size_t)(i0 + ii) * DD + j0 + jj4 * 4);
  }
  // Norm partials (only the jc==0 slice of the grid emits them).
  if (blockIdx.y == 0)
    ws_t[(size_t)(NTP + blockIdx.z * 4 + wv) * BB + b0 + lane] = nrm;
  __syncthreads();

  // acc[r][c] = sum_i xd[b0+8tb+r, i] * W[i, j0+4tj+c]
  float acc[8][4] = {};
#pragma unroll
  for (int i = 0; i < KT; ++i) {
    const float4 xlo = *(const float4*)&xd_t[i][tb * 8];      // 2 uniq/wave
    const float4 xhi = *(const float4*)&xd_t[i][tb * 8 + 4];
    const float4 w   = *(const float4*)&w_s[i][tj * 4];
    acc[0][0] += xlo.x * w.x; acc[0][1] += xlo.x * w.y;
    acc[0][2] += xlo.x * w.z; acc[0][3] += xlo.x * w.w;
    acc[1][0] += xlo.y * w.x; acc[1][1] += xlo.y * w.y;
    acc[1][2] += xlo.y * w.z; acc[1][3] += xlo.y * w.w;
    acc[2][0] += xlo.z * w.x; acc[2][1] += xlo.z * w.y;
    acc[2][2] += xlo.z * w.z; acc[2][3] += xlo.z * w.w;
    acc[3][0] += xlo.w * w.x; acc[3][1] += xlo.w * w.y;
    acc[3][2] += xlo.w * w.z; acc[3][3] += xlo.w * w.w;
    acc[4][0] += xhi.x * w.x; acc[4][1] += xhi.x * w.y;
    acc[4][2] += xhi.x * w.z; acc[4][3] += xhi.x * w.w;
    acc[5][0] += xhi.y * w.x; acc[5][1] += xhi.y * w.y;
    acc[5][2] += xhi.y * w.z; acc[5][3] += xhi.y * w.w;
    acc[6][0] += xhi.z * w.x; acc[6][1] += xhi.z * w.y;
    acc[6][2] += xhi.z * w.z; acc[6][3] += xhi.z * w.w;
    acc[7][0] += xhi.w * w.x; acc[7][1] += xhi.w * w.y;
    acc[7][2] += xhi.w * w.z; acc[7][3] += xhi.w * w.w;
  }

  // Contract with x over this thread's 4 j's (L2-hit loads), reduce over tj.
  float tp[8];
#pragma unroll
  for (int r = 0; r < 8; ++r) {
    const float4 xv =
        *(const float4*)(x + (size_t)(b0 + tb * 8 + r) * DD + j0 + tj * 4);
    tp[r] = acc[r][0] * xv.x + acc[r][1] * xv.y +
            acc[r][2] * xv.z + acc[r][3] * xv.w;
  }
#pragma unroll
  for (int off = 16; off >= 1; off >>= 1) {
#pragma unroll
    for (int r = 0; r < 8; ++r) tp[r] += __shfl_xor(tp[r], off);
  }
  if (tj == 0) {
    const int p = blockIdx.y * NIC + blockIdx.z;   // 0..63
    float* dst = ws_t + (size_t)p * BB + b0 + tb * 8;
    *(float4*)(dst + 0) = make_float4(tp[0], tp[1], tp[2], tp[3]);
    *(float4*)(dst + 4) = make_float4(tp[4], tp[5], tp[6], tp[7]);
  }
}

// k2: one thread per b. out[b] = (sum norm partials) + (sum t partials)^2.
// 512 KB of partials, L2-resident, fully coalesced across b.
__global__ __launch_bounds__(256) void stm_final_kernel(
    const float* __restrict__ ws_t, float* __restrict__ out) {
  const int b = blockIdx.x * 256 + threadIdx.x;
  float t = 0.f, n = 0.f;
#pragma unroll
  for (int p = 0; p < NTP; ++p) t += ws_t[(size_t)p * BB + b];
#pragma unroll
  for (int p = 0; p < NNP; ++p) n += ws_t[(size_t)(NTP + p) * BB + b];
  out[b] = n + t * t;
}

extern "C" void kernel_launch(void* const* d_in, const int* in_sizes, int n_in,
                              void* d_out, int out_size, void* d_ws, size_t ws_size,
                              hipStream_t stream) {
  const float* x    = (const float*)d_in[0];
  const float* xdot = (const float*)d_in[1];
  const float* W    = (const float*)d_in[2];
  float* ws = (float*)d_ws;   // 128 * 1024 floats = 512 KB of partials
  float* out = (float*)d_out;

  dim3 g1(BB / BT, DD / JT, NIC);  // (16, 4, 16) = 1024 blocks
  stm_main_kernel<<<g1, 256, 0, stream>>>(x, xdot, W, ws);
  stm_final_kernel<<<BB / 256, 256, 0, stream>>>(ws, out);
}